// Round 15
// baseline (76.969 us; speedup 1.0000x reference)
//
#include <hip/hip_runtime.h>

#define B_ 256
#define M_ 512
#define N_ 256
#define K_ 16
#define TR 64                 // rows per LDS tile
#define NT 4                  // tiles per block (256 rows)
#define NBLK (B_ * 2)         // 512 blocks, 2/CU, all co-resident

typedef __attribute__((ext_vector_type(8))) short short8;
typedef __attribute__((ext_vector_type(4))) float f32x4;

__device__ __forceinline__ unsigned short f2bf(float f) {
    unsigned u = __builtin_bit_cast(unsigned, f);
    u += 0x7FFFu + ((u >> 16) & 1u);       // round-to-nearest-even
    return (unsigned short)(u >> 16);
}
__device__ __forceinline__ float bf2f(unsigned short h) {
    unsigned u = ((unsigned)h) << 16;
    return __builtin_bit_cast(float, u);
}

// ---------------- Fused FM: R12 main loop + pairwise sibling sync ----------------
// grid = 512 blocks (2 per batch, 2/CU), 256 threads (4 waves).
// Main loop byte-equivalent to R12/R14 champion (sequential fp32 streaming,
// bf16 LDS tile, persistent vB, MFMA 16x16x32, in-loop linear term -> LDS).
// Epilogue: xv never leaves registers. Block publishes its 16-float sv
// partial (agent release stores) + flag; spins ONLY on its sibling's flag
// (blk^1, co-resident by capacity, launched adjacently -> ~zero wait).
// Then q = xv.(sv - xv) per row via shuffles; single out write.
__global__ __launch_bounds__(256) void fm_fused(
    const float* __restrict__ x, const float* __restrict__ w,
    const float* __restrict__ bias, const float* __restrict__ v,
    float* __restrict__ svpart, int* __restrict__ flags,
    float* __restrict__ out)
{
    __shared__ __align__(16) unsigned char xL[2][TR * 512];  // 2 x 32 KiB bf16
    __shared__ __align__(16) unsigned short wLb[N_];         // w bf16
    __shared__ __align__(16) float lin[NT * TR];             // linear terms, 1 KiB
    __shared__ __align__(16) float red[64];
    __shared__ __align__(16) float svO[16];                  // own sv partial

    const int t   = threadIdx.x;
    const int l   = t & 63;
    const int wv  = t >> 6;
    const int blk = blockIdx.x;
    const int b   = blk >> 1;
    const int m0  = (blk & 1) * (NT * TR);
    const int sib = blk ^ 1;
    const float bias0 = bias[0];

    // stage w as bf16
    if (t < 64) {
        float4 wq = *(const float4*)(w + t * 4);
        wLb[t * 4 + 0] = f2bf(wq.x); wLb[t * 4 + 1] = f2bf(wq.y);
        wLb[t * 4 + 2] = f2bf(wq.z); wLb[t * 4 + 3] = f2bf(wq.w);
    }

    // B-fragments: v -> bf16, 8 n-chunks, persistent in registers.
    // 16x16x32 bf16 layout: B[k][col]: col = l&15, k = (l>>4)*8 + j.
    short8 vB[8];
    #pragma unroll
    for (int c = 0; c < 8; ++c) {
        #pragma unroll
        for (int j = 0; j < 8; ++j) {
            float f = v[(size_t)(c * 32 + (l >> 4) * 8 + j) * K_ + (l & 15)];
            vB[c][j] = (short)f2bf(f);
        }
    }

    const float* gx = x + (size_t)(b * M_ + m0) * N_;

    // staging: load j covers rows [j*4, j*4+4), wave wv -> row j*4+wv,
    // lane l -> floats [l*4, l*4+4). 1 KB contiguous per wave-instr, sequential.
    const int swq = l >> 1;
    const int shf = (l & 1) * 8;

    float4 st[16];
    // prologue: tile 0 -> regs -> bf16 -> buf 0
    #pragma unroll
    for (int j = 0; j < 16; ++j)
        st[j] = *(const float4*)(gx + j * 1024 + t * 4);
    #pragma unroll
    for (int j = 0; j < 16; ++j) {
        const int row = j * 4 + wv;
        unsigned lo = (unsigned)f2bf(st[j].x) | ((unsigned)f2bf(st[j].y) << 16);
        unsigned hi = (unsigned)f2bf(st[j].z) | ((unsigned)f2bf(st[j].w) << 16);
        unsigned* d = (unsigned*)(xL[0] + row * 512 + ((swq ^ (row & 7)) << 4) + shf);
        d[0] = lo; d[1] = hi;
    }
    __syncthreads();

    f32x4 acc[NT];
    #pragma unroll
    for (int T = 0; T < NT; ++T) acc[T] = f32x4{0.f, 0.f, 0.f, 0.f};

    #pragma unroll
    for (int T = 0; T < NT; ++T) {
        const int cur = T & 1;
        if (T + 1 < NT) {
            #pragma unroll
            for (int j = 0; j < 16; ++j)
                st[j] = *(const float4*)(gx + (size_t)(T + 1) * TR * N_ + j * 1024 + t * 4);
        }

        // MFMA: wave wv, rows [wv*16, +16). A[row][k]: row = l&15, k = (l>>4)*8+j.
        const int arow = wv * 16 + (l & 15);
        const unsigned char* abase = xL[cur] + arow * 512;
        #pragma unroll
        for (int c = 0; c < 8; ++c) {
            short8 a = *(const short8*)(abase + (((c * 4 + (l >> 4)) ^ (arow & 7)) << 4));
            acc[T] = __builtin_amdgcn_mfma_f32_16x16x32_bf16(a, vB[c], acc[T], 0, 0, 0);
        }

        // linear term: 4 threads/row, 64-col quarters -> lin[] (LDS)
        {
            const int row = t >> 2;
            const int qt  = t & 3;
            const unsigned char* rbase = xL[cur] + row * 512;
            float ls = 0.f;
            #pragma unroll
            for (int i = 0; i < 8; ++i) {
                short8 xs = *(const short8*)(rbase + ((((qt * 8 + i)) ^ (row & 7)) << 4));
                short8 ws = *(const short8*)((const unsigned char*)wLb + qt * 128 + i * 16);
                #pragma unroll
                for (int e = 0; e < 8; ++e)
                    ls += bf2f((unsigned short)xs[e]) * bf2f((unsigned short)ws[e]);
            }
            ls += __shfl_xor(ls, 1);
            ls += __shfl_xor(ls, 2);
            if (qt == 0) lin[T * TR + row] = ls;
        }

        if (T + 1 < NT) {
            #pragma unroll
            for (int j = 0; j < 16; ++j) {
                const int row = j * 4 + wv;
                unsigned lo = (unsigned)f2bf(st[j].x) | ((unsigned)f2bf(st[j].y) << 16);
                unsigned hi = (unsigned)f2bf(st[j].z) | ((unsigned)f2bf(st[j].w) << 16);
                unsigned* d = (unsigned*)(xL[cur ^ 1] + row * 512 + ((swq ^ (row & 7)) << 4) + shf);
                d[0] = lo; d[1] = hi;
            }
        }
        __syncthreads();
    }

    // ---- own sv partial: per-lane row-sum, shfl 16/32, cross-wave via LDS ----
    float s = 0.f;
    #pragma unroll
    for (int T = 0; T < NT; ++T)
        s += acc[T][0] + acc[T][1] + acc[T][2] + acc[T][3];
    s += __shfl_xor(s, 16);
    s += __shfl_xor(s, 32);
    if (l < 16) red[wv * 16 + l] = s;
    __syncthreads();
    if (t < 16) {
        const float p = red[t] + red[16 + t] + red[32 + t] + red[48 + t];
        svO[t] = p;
        __hip_atomic_store(svpart + (size_t)blk * 16 + t, p,
                           __ATOMIC_RELEASE, __HIP_MEMORY_SCOPE_AGENT);
    }
    __syncthreads();

    // ---- pairwise sync with sibling block (blk^1) ----
    if (t == 0) {
        __threadfence();
        __hip_atomic_store(flags + blk, 1, __ATOMIC_RELEASE, __HIP_MEMORY_SCOPE_AGENT);
        while (__hip_atomic_load(flags + sib, __ATOMIC_ACQUIRE,
                                 __HIP_MEMORY_SCOPE_AGENT) == 0)
            __builtin_amdgcn_s_sleep(1);
    }
    __syncthreads();

    // ---- sv for batch = own + sibling partial (fixed order: deterministic) ----
    const float svk = svO[l & 15] +
        __hip_atomic_load(svpart + (size_t)sib * 16 + (l & 15),
                          __ATOMIC_RELAXED, __HIP_MEMORY_SCOPE_AGENT);

    // ---- pairwise term from registers; single out write ----
    // C/D layout: k = l&15, row = T*64 + wv*16 + (l>>4)*4 + r.
    #pragma unroll
    for (int T = 0; T < NT; ++T) {
        #pragma unroll
        for (int r = 0; r < 4; ++r) {
            const float a = acc[T][r];
            float q = a * (svk - a);
            q += __shfl_xor(q, 1);
            q += __shfl_xor(q, 2);
            q += __shfl_xor(q, 4);
            q += __shfl_xor(q, 8);
            if ((l & 15) == 0) {
                const int row = T * TR + wv * 16 + (l >> 4) * 4 + r;
                out[(size_t)b * M_ + m0 + row] = lin[row] + bias0 + 0.5f * q;
            }
        }
    }
}

extern "C" void kernel_launch(void* const* d_in, const int* in_sizes, int n_in,
                              void* d_out, int out_size, void* d_ws, size_t ws_size,
                              hipStream_t stream) {
    const float* x    = (const float*)d_in[0];
    const float* w    = (const float*)d_in[1];
    const float* bias = (const float*)d_in[2];
    const float* v    = (const float*)d_in[3];
    float* out = (float*)d_out;

    float* svpart = (float*)d_ws;                        // 512*16 floats = 32 KiB
    int*   flags  = (int*)((char*)d_ws + (64 << 10));    // 512 ints

    hipMemsetAsync(flags, 0, NBLK * sizeof(int), stream);  // reset per launch
    fm_fused<<<dim3(NBLK), dim3(256), 0, stream>>>(x, w, bias, v, svpart, flags, out);
}

// Round 16
// 29.762 us; speedup vs baseline: 2.5861x; 2.5861x over previous
//
#include <hip/hip_runtime.h>

#define B_ 256
#define M_ 512
#define N_ 256
#define K_ 16
#define TR 32                 // rows per LDS tile
#define NT 4                  // tiles per block (128 rows)
#define BPB 4                 // blocks per batch

typedef __attribute__((ext_vector_type(8))) short short8;
typedef __attribute__((ext_vector_type(4))) float f32x4;

__device__ __forceinline__ unsigned short f2bf(float f) {
    unsigned u = __builtin_bit_cast(unsigned, f);
    u += 0x7FFFu + ((u >> 16) & 1u);       // round-to-nearest-even
    return (unsigned short)(u >> 16);
}
__device__ __forceinline__ float bf2f(unsigned short h) {
    unsigned u = ((unsigned)h) << 16;
    return __builtin_bit_cast(float, u);
}

// ---------------- Pass 1 (R14 structure at 4 blocks/CU) ----------------
// grid = B_*4 = 1024 blocks (4/CU, ~34 KB LDS), 256 threads (4 waves).
// Block owns 128 rows = 4 tiles x 32 rows x 256 cols.
// Wave wv = (wr = wv&1: rows [wr*16,+16) of tile; wn = wv>>1: n-half).
// Per tile: stage 8 seq float4 rounds -> bf16 swizzled LDS; 4 MFMA/wave;
// linear term 8 thr/row from LDS. Epilogue: block-local wn-combine (LDS),
// xv -> global bf16, sv partial fp32. NO cross-block sync (hard lesson).
__global__ __launch_bounds__(256) void fm_pass1(
    const float* __restrict__ x, const float* __restrict__ w,
    const float* __restrict__ bias, const float* __restrict__ v,
    unsigned short* __restrict__ xvb, float* __restrict__ svpart,
    float* __restrict__ out)
{
    __shared__ __align__(16) unsigned char xL[2][TR * 512];  // 2 x 16 KiB bf16
    __shared__ __align__(16) unsigned short wLb[N_];         // w bf16, 512 B
    __shared__ __align__(16) float red[32];
    __shared__ __align__(16) float exch[2 * 64 * 16];        // 8 KiB wn-exchange

    const int t   = threadIdx.x;
    const int l   = t & 63;
    const int wv  = t >> 6;
    const int wr  = wv & 1;         // row-half of tile
    const int wn  = wv >> 1;        // n-half
    const int blk = blockIdx.x;
    const int b   = blk >> 2;
    const int m0  = (blk & 3) * (NT * TR);
    const float bias0 = bias[0];

    // stage w as bf16
    if (t < 64) {
        float4 wq = *(const float4*)(w + t * 4);
        wLb[t * 4 + 0] = f2bf(wq.x); wLb[t * 4 + 1] = f2bf(wq.y);
        wLb[t * 4 + 2] = f2bf(wq.z); wLb[t * 4 + 3] = f2bf(wq.w);
    }

    // B-fragments for this wave's n-half: chunks wn*4..+3 (32 n each).
    // 16x16x32 bf16 B layout: col = l&15, k = (l>>4)*8 + j.
    short8 vB[4];
    #pragma unroll
    for (int c = 0; c < 4; ++c) {
        #pragma unroll
        for (int j = 0; j < 8; ++j) {
            float f = v[(size_t)((wn * 4 + c) * 32 + (l >> 4) * 8 + j) * K_ + (l & 15)];
            vB[c][j] = (short)f2bf(f);
        }
    }

    const float* gx = x + (size_t)(b * M_ + m0) * N_;

    // staging: round j covers rows [j*4, j*4+4): thread -> row j*4+wv,
    // floats [l*4, l*4+4). 1 KB contiguous per wave-instr, block-sequential.
    const int swq = l >> 1;
    const int shf = (l & 1) * 8;

    float4 st[8];
    // prologue: tile 0 -> regs -> bf16 -> buf 0
    #pragma unroll
    for (int j = 0; j < 8; ++j)
        st[j] = *(const float4*)(gx + j * 1024 + t * 4);
    #pragma unroll
    for (int j = 0; j < 8; ++j) {
        const int row = j * 4 + wv;
        unsigned lo = (unsigned)f2bf(st[j].x) | ((unsigned)f2bf(st[j].y) << 16);
        unsigned hi = (unsigned)f2bf(st[j].z) | ((unsigned)f2bf(st[j].w) << 16);
        unsigned* d = (unsigned*)(xL[0] + row * 512 + ((swq ^ (row & 7)) << 4) + shf);
        d[0] = lo; d[1] = hi;
    }
    __syncthreads();

    f32x4 acc[NT];
    #pragma unroll
    for (int T = 0; T < NT; ++T) acc[T] = f32x4{0.f, 0.f, 0.f, 0.f};
    float lin[NT];   // this thread's linear-term share (row t>>3 of each tile)

    #pragma unroll
    for (int T = 0; T < NT; ++T) {
        const int cur = T & 1;
        if (T + 1 < NT) {
            #pragma unroll
            for (int j = 0; j < 8; ++j)
                st[j] = *(const float4*)(gx + (size_t)(T + 1) * TR * N_ + j * 1024 + t * 4);
        }

        // MFMA: rows [wr*16,+16), chunks wn*4..+3. A: row=l&15, k=(l>>4)*8+j.
        const int arow = wr * 16 + (l & 15);
        const unsigned char* abase = xL[cur] + arow * 512;
        #pragma unroll
        for (int c = 0; c < 4; ++c) {
            const int cq = (wn * 4 + c) * 4 + (l >> 4);
            short8 a = *(const short8*)(abase + ((cq ^ (arow & 7)) << 4));
            acc[T] = __builtin_amdgcn_mfma_f32_16x16x32_bf16(a, vB[c], acc[T], 0, 0, 0);
        }

        // linear term: 8 threads/row (row = t>>3, qt = t&7), 32-col chunks
        {
            const int row = t >> 3;
            const int qt  = t & 7;
            const unsigned char* rbase = xL[cur] + row * 512;
            float ls = 0.f;
            #pragma unroll
            for (int i = 0; i < 4; ++i) {
                const int qi = qt * 4 + i;
                short8 xs = *(const short8*)(rbase + ((qi ^ (row & 7)) << 4));
                short8 ws = *(const short8*)((const unsigned char*)wLb + qi * 16);
                #pragma unroll
                for (int e = 0; e < 8; ++e)
                    ls += bf2f((unsigned short)xs[e]) * bf2f((unsigned short)ws[e]);
            }
            ls += __shfl_xor(ls, 1);
            ls += __shfl_xor(ls, 2);
            ls += __shfl_xor(ls, 4);
            lin[T] = ls;
        }

        if (T + 1 < NT) {
            #pragma unroll
            for (int j = 0; j < 8; ++j) {
                const int row = j * 4 + wv;
                unsigned lo = (unsigned)f2bf(st[j].x) | ((unsigned)f2bf(st[j].y) << 16);
                unsigned hi = (unsigned)f2bf(st[j].z) | ((unsigned)f2bf(st[j].w) << 16);
                unsigned* d = (unsigned*)(xL[cur ^ 1] + row * 512 + ((swq ^ (row & 7)) << 4) + shf);
                d[0] = lo; d[1] = hi;
            }
        }
        __syncthreads();
    }

    // linear-term writes (out): thread (t&7)==0 owns row t>>3 of each tile
    if ((t & 7) == 0) {
        #pragma unroll
        for (int T = 0; T < NT; ++T)
            out[(size_t)b * M_ + m0 + T * TR + (t >> 3)] = lin[T] + bias0;
    }

    // ---- combine n-halves (block-local): wn==1 publish, wn==0 add ----
    {
        float* dst = exch + (size_t)(wr * 64 + l) * 16;
        if (wn == 1) {
            #pragma unroll
            for (int T = 0; T < NT; ++T)
                *(f32x4*)(dst + T * 4) = acc[T];
        }
    }
    __syncthreads();
    if (wn == 0) {
        const float* src = exch + (size_t)(wr * 64 + l) * 16;
        #pragma unroll
        for (int T = 0; T < NT; ++T) {
            f32x4 o = *(const f32x4*)(src + T * 4);
            acc[T][0] += o[0]; acc[T][1] += o[1];
            acc[T][2] += o[2]; acc[T][3] += o[3];
        }

        // xv -> global bf16. C/D layout: k=l&15, row=T*32 + wr*16 + (l>>4)*4 + r.
        #pragma unroll
        for (int T = 0; T < NT; ++T) {
            const int rbase = m0 + T * TR + wr * 16 + (l >> 4) * 4;
            #pragma unroll
            for (int r = 0; r < 4; ++r)
                xvb[(size_t)(b * M_ + rbase + r) * K_ + (l & 15)] = f2bf(acc[T][r]);
        }

        // sv partial: per-lane row-sum, shfl 16/32, cross-wave (wr) via LDS
        float s = 0.f;
        #pragma unroll
        for (int T = 0; T < NT; ++T)
            s += acc[T][0] + acc[T][1] + acc[T][2] + acc[T][3];
        s += __shfl_xor(s, 16);
        s += __shfl_xor(s, 32);
        if (l < 16) red[wr * 16 + l] = s;
    }
    __syncthreads();
    if (t < 16)
        svpart[(size_t)blk * 16 + t] = red[t] + red[16 + t];
}

// ---------------- Pass 2 (bf16 xv read; 4 svparts per batch) ----------------
__global__ __launch_bounds__(256) void fm_pass2(
    const unsigned short* __restrict__ xvb, const float* __restrict__ svpart,
    float* __restrict__ out)
{
    const int t = threadIdx.x;
    const int blk = blockIdx.x;
    const int b = blk >> 1;
    const int m = (blk & 1) * 256 + t;
    __shared__ __align__(16) float svL[16];
    if (t < 16) {
        float s = 0.f;
        #pragma unroll
        for (int j = 0; j < BPB; ++j)
            s += svpart[(size_t)(b * BPB + j) * 16 + t];
        svL[t] = s;
    }
    __syncthreads();

    const unsigned short* xp = xvb + ((size_t)b * M_ + m) * K_;
    short8 h0 = *(const short8*)(xp);
    short8 h1 = *(const short8*)(xp + 8);

    float rs = 0.f, dg = 0.f;
    #pragma unroll
    for (int k = 0; k < 8; ++k) {
        const float a = bf2f((unsigned short)h0[k]);
        rs += a * svL[k];
        dg += a * a;
    }
    #pragma unroll
    for (int k = 0; k < 8; ++k) {
        const float a = bf2f((unsigned short)h1[k]);
        rs += a * svL[8 + k];
        dg += a * a;
    }

    const size_t o = (size_t)b * M_ + m;
    out[o] = out[o] + 0.5f * (rs - dg);
}

extern "C" void kernel_launch(void* const* d_in, const int* in_sizes, int n_in,
                              void* d_out, int out_size, void* d_ws, size_t ws_size,
                              hipStream_t stream) {
    const float* x    = (const float*)d_in[0];
    const float* w    = (const float*)d_in[1];
    const float* bias = (const float*)d_in[2];
    const float* v    = (const float*)d_in[3];
    float* out = (float*)d_out;

    unsigned short* xvb = (unsigned short*)d_ws;            // B*M*K bf16 = 4 MiB
    float* svpart = (float*)((char*)d_ws + ((size_t)B_ * M_ * K_ * 2));

    fm_pass1<<<dim3(B_ * BPB), dim3(256), 0, stream>>>(x, w, bias, v, xvb, svpart, out);
    fm_pass2<<<dim3(B_ * 2), dim3(256), 0, stream>>>(xvb, svpart, out);
}